// Round 10
// baseline (521.671 us; speedup 1.0000x reference)
//
#include <hip/hip_runtime.h>

// WeightedLoss: loss_i = (target_i == 1) ? 1 - sigmoid(pred_i) : 0.1 ; out = mean(loss)
// 1 - sigmoid(x) = 1 / (1 + exp(x))
//
// R9 post-mortem: nt (non-temporal) loads gave ~155 -> ~130us kernel — L2
// allocation thrash was real. R10: fix the LAST untouched lever — grid
// granularity. 2048 blocks x 4 waves was EXACTLY 1.0x the 8192 wave slots
// (no oversubscription; stragglers leave CUs idle; occupancy 65%). Now
// 8192 blocks x 8 iters: 4x oversubscription, fine-grained load balance.
// Structure otherwise identical to R9 (depth-2 pipe + nt loads).

#define BLOCK 256
#define GRID  8192   // 32 blocks/CU queued, 4x wave-slot oversubscription

typedef float vf4 __attribute__((ext_vector_type(4)));
typedef int   vi4 __attribute__((ext_vector_type(4)));

__device__ __forceinline__ float loss4(vf4 p, vi4 t) {
    float l0 = (t.x == 1) ? 1.0f / (1.0f + __expf(p.x)) : 0.1f;
    float l1 = (t.y == 1) ? 1.0f / (1.0f + __expf(p.y)) : 0.1f;
    float l2 = (t.z == 1) ? 1.0f / (1.0f + __expf(p.z)) : 0.1f;
    float l3 = (t.w == 1) ? 1.0f / (1.0f + __expf(p.w)) : 0.1f;
    return (l0 + l1) + (l2 + l3);
}

__device__ __forceinline__ void block_reduce_atomic(float acc, float inv_n,
                                                    float* __restrict__ out) {
#pragma unroll
    for (int off = 32; off > 0; off >>= 1)
        acc += __shfl_down(acc, off, 64);
    __shared__ float smem[BLOCK / 64];
    const int lane = threadIdx.x & 63;
    const int wave = threadIdx.x >> 6;
    if (lane == 0) smem[wave] = acc;
    __syncthreads();
    if (threadIdx.x == 0) {
        float bsum = (smem[0] + smem[1]) + (smem[2] + smem[3]);
        atomicAdd(out, bsum * inv_n);
    }
}

// Depth-2 software pipeline + nt loads (R9 structure, finer grid).
__global__ __launch_bounds__(BLOCK)
void wloss_nt(const vf4* __restrict__ p4,
              const vi4* __restrict__ t4,
              float* __restrict__ out,
              int iters, int stride, float inv_n) {
    int i = blockIdx.x * BLOCK + threadIdx.x;

    vf4 pA = __builtin_nontemporal_load(&p4[i]);
    vi4 tA = __builtin_nontemporal_load(&t4[i]);
    vf4 pB = __builtin_nontemporal_load(&p4[i + stride]);
    vi4 tB = __builtin_nontemporal_load(&t4[i + stride]);
    int idx = i + 2 * stride;

    float acc = 0.0f;
    for (int k = 0; k < iters - 2; ++k) {
        vf4 pN = __builtin_nontemporal_load(&p4[idx]);
        vi4 tN = __builtin_nontemporal_load(&t4[idx]);
        idx += stride;
        acc += loss4(pA, tA);
        pA = pB; tA = tB;
        pB = pN; tB = tN;
    }
    acc += loss4(pA, tA);
    acc += loss4(pB, tB);

    block_reduce_atomic(acc, inv_n, out);
}

// Generic fallback for arbitrary n.
__global__ __launch_bounds__(BLOCK)
void wloss_generic(const float* __restrict__ pred,
                   const int*   __restrict__ tgt,
                   float* __restrict__ out,
                   long long n, float inv_n) {
    const long long n4     = n >> 2;
    const long long tid    = (long long)blockIdx.x * blockDim.x + threadIdx.x;
    const long long stride = (long long)gridDim.x * blockDim.x;

    const vf4* p4 = (const vf4*)pred;
    const vi4* t4 = (const vi4*)tgt;

    float acc = 0.0f;
    for (long long i = tid; i < n4; i += stride)
        acc += loss4(p4[i], t4[i]);
    if (blockIdx.x == 0) {
        for (long long i = (n4 << 2) + threadIdx.x; i < n; i += blockDim.x)
            acc += (tgt[i] == 1) ? 1.0f / (1.0f + __expf(pred[i])) : 0.1f;
    }
    block_reduce_atomic(acc, inv_n, out);
}

extern "C" void kernel_launch(void* const* d_in, const int* in_sizes, int n_in,
                              void* d_out, int out_size, void* d_ws, size_t ws_size,
                              hipStream_t stream) {
    const float* pred = (const float*)d_in[0];
    const int*   tgt  = (const int*)d_in[1];
    float*       out  = (float*)d_out;

    const long long n = (long long)in_sizes[0];
    const float inv_n = 1.0f / (float)n;

    hipMemsetAsync(out, 0, sizeof(float), stream);

    const long long n4 = n >> 2;
    const long long stride = (long long)GRID * BLOCK;   // 2^21 float4/step

    if ((n & 3) == 0 && n4 % stride == 0 && n4 / stride >= 2) {
        const int iters = (int)(n4 / stride);           // 8 for N=2^26
        wloss_nt<<<GRID, BLOCK, 0, stream>>>((const vf4*)pred,
                                             (const vi4*)tgt, out,
                                             iters, (int)stride, inv_n);
    } else {
        long long g = (n4 + BLOCK - 1) / BLOCK;
        if (g > 8192) g = 8192;
        if (g < 1)    g = 1;
        wloss_generic<<<(int)g, BLOCK, 0, stream>>>(pred, tgt, out, n, inv_n);
    }
}

// Round 11
// 483.910 us; speedup vs baseline: 1.0780x; 1.0780x over previous
//
#include <hip/hip_runtime.h>

// WeightedLoss: loss_i = (target_i == 1) ? 1 - sigmoid(pred_i) : 0.1 ; out = mean(loss)
// 1 - sigmoid(x) = 1 / (1 + exp(x))
//
// R10 post-mortem: 4x grid oversubscription (8192 blocks x 8 iters) REGRESSED
// (~136 -> ~177us kernel): pipeline ramp = 25% of traffic at 8 iters vs 6% at
// 32, plus block churn. Grid curve: 2048 best, 8192 worse.
// R11 = exact replay of R9 (best measured: GRID 2048, depth-2 pipe, nt loads)
// as the reproducibility control before declaring the read-path plateau.
// Ledger: depth {1,2,8}: 2 best. nt: -20% (L2 thrash real). grid {2048,8192}:
// 2048 best. Little's law rules out latency-depth as limiter at ~4.1 TB/s —
// throughput cap on the read path (~512 GB/s/XCD L2-miss/fabric read rate).

#define BLOCK 256
#define GRID  2048   // 8 blocks/CU — measured best (R9)

typedef float vf4 __attribute__((ext_vector_type(4)));
typedef int   vi4 __attribute__((ext_vector_type(4)));

__device__ __forceinline__ float loss4(vf4 p, vi4 t) {
    float l0 = (t.x == 1) ? 1.0f / (1.0f + __expf(p.x)) : 0.1f;
    float l1 = (t.y == 1) ? 1.0f / (1.0f + __expf(p.y)) : 0.1f;
    float l2 = (t.z == 1) ? 1.0f / (1.0f + __expf(p.z)) : 0.1f;
    float l3 = (t.w == 1) ? 1.0f / (1.0f + __expf(p.w)) : 0.1f;
    return (l0 + l1) + (l2 + l3);
}

__device__ __forceinline__ void block_reduce_atomic(float acc, float inv_n,
                                                    float* __restrict__ out) {
#pragma unroll
    for (int off = 32; off > 0; off >>= 1)
        acc += __shfl_down(acc, off, 64);
    __shared__ float smem[BLOCK / 64];
    const int lane = threadIdx.x & 63;
    const int wave = threadIdx.x >> 6;
    if (lane == 0) smem[wave] = acc;
    __syncthreads();
    if (threadIdx.x == 0) {
        float bsum = (smem[0] + smem[1]) + (smem[2] + smem[3]);
        atomicAdd(out, bsum * inv_n);
    }
}

// Depth-2 software pipeline + nt loads (exact R9 structure).
__global__ __launch_bounds__(BLOCK)
void wloss_nt(const vf4* __restrict__ p4,
              const vi4* __restrict__ t4,
              float* __restrict__ out,
              int iters, int stride, float inv_n) {
    int i = blockIdx.x * BLOCK + threadIdx.x;

    vf4 pA = __builtin_nontemporal_load(&p4[i]);
    vi4 tA = __builtin_nontemporal_load(&t4[i]);
    vf4 pB = __builtin_nontemporal_load(&p4[i + stride]);
    vi4 tB = __builtin_nontemporal_load(&t4[i + stride]);
    int idx = i + 2 * stride;

    float acc = 0.0f;
    for (int k = 0; k < iters - 2; ++k) {
        vf4 pN = __builtin_nontemporal_load(&p4[idx]);
        vi4 tN = __builtin_nontemporal_load(&t4[idx]);
        idx += stride;
        acc += loss4(pA, tA);
        pA = pB; tA = tB;
        pB = pN; tB = tN;
    }
    acc += loss4(pA, tA);
    acc += loss4(pB, tB);

    block_reduce_atomic(acc, inv_n, out);
}

// Generic fallback for arbitrary n.
__global__ __launch_bounds__(BLOCK)
void wloss_generic(const float* __restrict__ pred,
                   const int*   __restrict__ tgt,
                   float* __restrict__ out,
                   long long n, float inv_n) {
    const long long n4     = n >> 2;
    const long long tid    = (long long)blockIdx.x * blockDim.x + threadIdx.x;
    const long long stride = (long long)gridDim.x * blockDim.x;

    const vf4* p4 = (const vf4*)pred;
    const vi4* t4 = (const vi4*)tgt;

    float acc = 0.0f;
    for (long long i = tid; i < n4; i += stride)
        acc += loss4(p4[i], t4[i]);
    if (blockIdx.x == 0) {
        for (long long i = (n4 << 2) + threadIdx.x; i < n; i += blockDim.x)
            acc += (tgt[i] == 1) ? 1.0f / (1.0f + __expf(pred[i])) : 0.1f;
    }
    block_reduce_atomic(acc, inv_n, out);
}

extern "C" void kernel_launch(void* const* d_in, const int* in_sizes, int n_in,
                              void* d_out, int out_size, void* d_ws, size_t ws_size,
                              hipStream_t stream) {
    const float* pred = (const float*)d_in[0];
    const int*   tgt  = (const int*)d_in[1];
    float*       out  = (float*)d_out;

    const long long n = (long long)in_sizes[0];
    const float inv_n = 1.0f / (float)n;

    hipMemsetAsync(out, 0, sizeof(float), stream);

    const long long n4 = n >> 2;
    const long long stride = (long long)GRID * BLOCK;   // 2^19 float4/step

    if ((n & 3) == 0 && n4 % stride == 0 && n4 / stride >= 2) {
        const int iters = (int)(n4 / stride);           // 32 for N=2^26
        wloss_nt<<<GRID, BLOCK, 0, stream>>>((const vf4*)pred,
                                             (const vi4*)tgt, out,
                                             iters, (int)stride, inv_n);
    } else {
        long long g = (n4 + BLOCK - 1) / BLOCK;
        if (g > 8192) g = 8192;
        if (g < 1)    g = 1;
        wloss_generic<<<(int)g, BLOCK, 0, stream>>>(pred, tgt, out, n, inv_n);
    }
}